// Round 16
// baseline (247.677 us; speedup 1.0000x reference)
//
#include <hip/hip_runtime.h>
#include <hip/hip_bf16.h>

#define NROW_F 8192
#define NROW_B 65536
#define KDIM   384
#define BM 128
#define BN 128
#define NSUB 16
#define NGRP (NROW_B / (BN * NSUB))      // 32
#define NBM  (NROW_F / BM)               // 64
#define NWG  (NBM * NGRP)                // 2048

// LDS (80 KB -> 2 blocks/CU): A staging 48K (prologue only), B tri-buf, sB
#define LDSA 0                 // 6 * 8192 = 49152
#define LDSB 49152             // 3 * 8192 = 24576
#define LDSS 73728             // 8192 (2048 f32 sB slice)
#define LDSR 49152             // epilogue red[2][128] aliases B
#define LDS_TOT 81920

typedef int   i32x4 __attribute__((ext_vector_type(4)));
typedef float f32x4 __attribute__((ext_vector_type(4)));

static __device__ __forceinline__ void stage16(const void* g, void* l) {
  __builtin_amdgcn_global_load_lds(
      (const __attribute__((address_space(1))) unsigned int*)g,
      (__attribute__((address_space(3))) unsigned int*)l, 16, 0, 0);
}

// ---------------------------------------------------------------------------
// 1) L2-normalize rows + symmetric i8 quantization with per-row scale.
// ---------------------------------------------------------------------------
__global__ __launch_bounds__(256) void quantize_rows_kernel(
    const float* __restrict__ in, char* __restrict__ out8,
    float* __restrict__ scales, int nrows) {
  int row  = blockIdx.x * 4 + (threadIdx.x >> 6);
  int lane = threadIdx.x & 63;
  if (row >= nrows) return;
  const float* r = in + (size_t)row * KDIM;
  float v[6];
  float ss = 0.f, mx = 0.f;
#pragma unroll
  for (int i = 0; i < 6; ++i) {
    v[i] = r[lane + i * 64];
    ss += v[i] * v[i];
    mx = fmaxf(mx, fabsf(v[i]));
  }
#pragma unroll
  for (int d = 1; d < 64; d <<= 1) {
    ss += __shfl_xor(ss, d, 64);
    mx = fmaxf(mx, __shfl_xor(mx, d, 64));
  }
  mx = fmaxf(mx, 1e-30f);
  float inv = rsqrtf(fmaxf(ss, 1e-24f));
  float scl = 127.0f / mx;
  if (lane == 0) scales[row] = mx * inv * (1.0f / 127.0f);
  char* o = out8 + (size_t)row * KDIM;
#pragma unroll
  for (int i = 0; i < 6; ++i)
    o[lane + i * 64] = (char)__float2int_rn(v[i] * scl);
}

// ---------------------------------------------------------------------------
// 2) maxsim: i8 MFMA 16x16x64. A panel in registers (a[6][4], read once);
//    B TRIPLE-buffered with COUNTED vmcnt(2) — r15's vmcnt(0) at phase top
//    put the leader-block's HBM latency (~900cy) on the critical path (T4:
//    never drain to 0 in the main loop). Prefetch distance now 2 phases.
//    Phase t: vmcnt(2) [B(t+1) landed; B(t+2),B(t+3) in flight] -> bar ->
//    4 ds_reads B(t+1) -> stage B(t+3)->buf t%3 (freed last phase) ->
//    16 MFMA on t's regs (no wait) -> lgkm(0) [reads land under MFMA].
// ---------------------------------------------------------------------------
__global__ __launch_bounds__(256, 2) void maxsim_kernel(
    const char* __restrict__ F8,    // 8192 x 384 i8
    const char* __restrict__ B8,    // 65536 x 384 i8
    const float* __restrict__ sA,   // 8192
    const float* __restrict__ sB,   // 65536
    float* __restrict__ partial) {  // NGRP x 8192 (max sim)
  __shared__ __align__(16) char smem[LDS_TOT];

  const int tid  = threadIdx.x;
  const int wv   = tid >> 6;         // 0..3
  const int lane = tid & 63;
  const int l15  = lane & 15;
  const int lhi  = lane >> 4;
  const int wr   = wv >> 1;          // 0..1 (row half)
  const int wc   = wv & 1;           // 0..1 (col half)

  // XCD-bijective swizzle (NWG % 8 == 0); consecutive wg share grp.
  const int wg  = (blockIdx.x & 7) * (NWG / 8) + (blockIdx.x >> 3);
  const int bm  = wg & (NBM - 1);
  const int grp = wg >> 6;
  const size_t brow = (size_t)bm * BM;

  const int srow = tid >> 2;                           // 0..63
  const int gsw  = (tid & 3) ^ ((tid >> 3) & 3);       // inverse write swizzle

  // A prologue: 6 K-tiles x 8KB (2 issues/thread each = 12)
  {
    const char* gA = F8 + (size_t)(brow + srow) * KDIM + gsw * 16;
    char* lA = smem + LDSA + wv * 1024;
#pragma unroll
    for (int kt = 0; kt < 6; ++kt) {
      stage16(gA + kt * 64,             lA + kt * 8192);
      stage16(gA + kt * 64 + 64 * KDIM, lA + kt * 8192 + 4096);
    }
  }
  // sB slice (2048 f32 = 8KB): PER-LANE source, 2 issues.
  {
    const char* gs = (const char*)(sB + (size_t)grp * 2048) + tid * 16;
    stage16(gs,        smem + LDSS + wv * 1024);
    stage16(gs + 4096, smem + LDSS + 4096 + wv * 1024);
  }

  auto stageB = [&](int s2, int koff, int buf) {
    const char* g = B8 + ((size_t)grp * 2048 + s2 * 128 + srow) * KDIM
                    + koff * 64 + gsw * 16;
    char* l = smem + LDSB + buf * 8192 + wv * 1024;
    stage16(g, l);
    stage16(g + (size_t)64 * KDIM, l + 4096);
  };
  stageB(0, 0, 0);   // B tile 0
  stageB(0, 1, 1);   // B tile 1
  stageB(0, 2, 2);   // B tile 2

  // read-side swizzle: chunk(lhi) ^= (row>>1)&3, row ≡ l15 (bases mult of 16)
  const int cof = ((l15 >> 1) & 3) << 4;

  auto ldA8 = [&](int k6, int m) -> i32x4 {
    int byte = k6 * 8192 + (wr * 64 + m * 16 + l15) * 64 + ((lhi << 4) ^ cof);
    return *reinterpret_cast<const i32x4*>(smem + LDSA + byte);
  };
  auto ldB8 = [&](int buf, int n) -> i32x4 {
    int byte = buf * 8192 + (wc * 64 + n * 16 + l15) * 64 + ((lhi << 4) ^ cof);
    return *reinterpret_cast<const i32x4*>(smem + LDSB + byte);
  };

  i32x4 acc[4][4];
  f32x4 vm[4];
#pragma unroll
  for (int m = 0; m < 4; ++m) {
    vm[m] = f32x4{-1e30f, -1e30f, -1e30f, -1e30f};
#pragma unroll
    for (int n = 0; n < 4; ++n) acc[m][n] = i32x4{0, 0, 0, 0};
  }

  // Prologue drain: 20 issues in-order -> vmcnt(4) = A + sB + B0 done,
  // B1,B2 (4 issues) still in flight.
  asm volatile("s_waitcnt vmcnt(4)" ::: "memory");
  __builtin_amdgcn_s_barrier();

  // Whole A panel -> registers (96 VGPR), read ONCE. Statically indexed.
  i32x4 a[6][4];
#pragma unroll
  for (int k6 = 0; k6 < 6; ++k6)
#pragma unroll
    for (int m = 0; m < 4; ++m) a[k6][m] = ldA8(k6, m);

  // cur B regs for t=0 (buf 0)
  i32x4 bA[4], bB[4];
#pragma unroll
  for (int n = 0; n < 4; ++n) bA[n] = ldB8(0, n);
  asm volatile("s_waitcnt lgkmcnt(0)" ::: "memory");

#define PHASE(K6, BC, BN_) do {                                               \
    asm volatile("s_waitcnt vmcnt(2)" ::: "memory");  /* B(t+1) landed     */ \
    __builtin_amdgcn_s_barrier();                     /* ALL waves' landed */ \
    __builtin_amdgcn_sched_barrier(0);                                        \
    _Pragma("unroll")                                                         \
    for (int n = 0; n < 4; ++n) BN_[n] = ldB8(((K6) + 1) % 3, n);             \
    {                                                                         \
      const int s2 = ((K6) < 3) ? sub : ((sub + 1) & (NSUB - 1));             \
      stageB(s2, ((K6) + 3) % 6, (K6) % 3);                                   \
    }                                                                         \
    __builtin_amdgcn_sched_barrier(0);                                        \
    __builtin_amdgcn_s_setprio(1);                                            \
    _Pragma("unroll")                                                         \
    for (int n = 0; n < 4; ++n)                                               \
      _Pragma("unroll")                                                       \
      for (int m = 0; m < 4; ++m)                                             \
        acc[m][n] = __builtin_amdgcn_mfma_i32_16x16x64_i8(                    \
            a[K6][m], BC[n], acc[m][n], 0, 0, 0);                             \
    __builtin_amdgcn_s_setprio(0);                                            \
    asm volatile("s_waitcnt lgkmcnt(0)" ::: "memory");                        \
    __builtin_amdgcn_sched_barrier(0);                                        \
  } while (0)

  for (int sub = 0; sub < NSUB; ++sub) {
    PHASE(0, bA, bB);
    PHASE(1, bB, bA);
    PHASE(2, bA, bB);
    PHASE(3, bB, bA);
    PHASE(4, bA, bB);
    PHASE(5, bB, bA);
    // fold subtile: vm = max(vm, acc * sB[col]); reset acc. sb from LDS.
    float sb[4];
#pragma unroll
    for (int n = 0; n < 4; ++n)
      sb[n] = *reinterpret_cast<const float*>(
          smem + LDSS + (sub * 128 + wc * 64 + n * 16 + l15) * 4);
#pragma unroll
    for (int m = 0; m < 4; ++m) {
#pragma unroll
      for (int n = 0; n < 4; ++n)
#pragma unroll
        for (int j = 0; j < 4; ++j)
          vm[m][j] = fmaxf(vm[m][j], (float)acc[m][n][j] * sb[n]);
#pragma unroll
      for (int n = 0; n < 4; ++n) acc[m][n] = i32x4{0, 0, 0, 0};
    }
  }
#undef PHASE

  // ---- epilogue ----
  asm volatile("s_waitcnt vmcnt(0)" ::: "memory");
#pragma unroll
  for (int d = 1; d < 16; d <<= 1)
#pragma unroll
    for (int m = 0; m < 4; ++m)
#pragma unroll
      for (int j = 0; j < 4; ++j)
        vm[m][j] = fmaxf(vm[m][j], __shfl_xor(vm[m][j], d, 64));

  float* red = (float*)(smem + LDSR);   // red[2][128] aliases B bufs
  __syncthreads();
  if (l15 == 0) {
#pragma unroll
    for (int m = 0; m < 4; ++m)
#pragma unroll
      for (int j = 0; j < 4; ++j)
        red[wc * 128 + wr * 64 + m * 16 + lhi * 4 + j] = vm[m][j];
  }
  __syncthreads();
  if (tid < BM) {
    float x = fmaxf(red[tid], red[128 + tid]);
    partial[(size_t)grp * NROW_F + brow + tid] = x * sA[brow + tid];
  }
}

// ---------------------------------------------------------------------------
// 3) combine partial maxes -> min_dists = clip(1 - max, 0, 2)
// ---------------------------------------------------------------------------
__global__ __launch_bounds__(256) void combine_kernel(
    const float* __restrict__ partial, float* __restrict__ md) {
  int r = blockIdx.x * 256 + threadIdx.x;
  if (r >= NROW_F) return;
  float m = -1e30f;
#pragma unroll
  for (int c = 0; c < NGRP; ++c) m = fmaxf(m, partial[(size_t)c * NROW_F + r]);
  float d = 1.0f - m;
  d = fminf(fmaxf(d, 0.0f), 2.0f);
  md[r] = d;
}

// ---------------------------------------------------------------------------
// 4) per-batch top-10 mean -> pred_score
// ---------------------------------------------------------------------------
__global__ __launch_bounds__(256) void topk_kernel(
    const float* __restrict__ md, float* __restrict__ out) {
  __shared__ float buf[1024];
  __shared__ float svals[256];
  __shared__ int   sidx[256];
  int b = blockIdx.x, tid = threadIdx.x;
  for (int i = tid; i < 1024; i += 256) buf[i] = md[b * 1024 + i];
  __syncthreads();
  float total = 0.f;
  for (int it = 0; it < 10; ++it) {
    float best = -1e30f; int bi = 0;
    for (int i = tid; i < 1024; i += 256)
      if (buf[i] > best) { best = buf[i]; bi = i; }
    svals[tid] = best; sidx[tid] = bi;
    __syncthreads();
    for (int s = 128; s > 0; s >>= 1) {
      if (tid < s && svals[tid + s] > svals[tid]) {
        svals[tid] = svals[tid + s]; sidx[tid] = sidx[tid + s];
      }
      __syncthreads();
    }
    if (tid == 0) { total += svals[0]; buf[sidx[0]] = -1e30f; }
    __syncthreads();
  }
  if (tid == 0) out[b] = total * 0.1f;
}

// ---------------------------------------------------------------------------
// 5) W = blur_1d ∘ bilinear_resize_1d : 448 x 32 operator.
// ---------------------------------------------------------------------------
__global__ __launch_bounds__(256) void build_w_kernel(float* __restrict__ W) {
  int idx = blockIdx.x * 256 + threadIdx.x;
  if (idx >= 448 * 32) return;
  int y = idx >> 5, g = idx & 31;
  float ksum = 0.f, acc = 0.f;
#pragma unroll
  for (int t = -16; t <= 16; ++t) {
    float ft = (float)t * 0.25f;
    float kv = expf(-0.5f * ft * ft);
    ksum += kv;
    int p = y + t;
    p = (p < 0) ? -p : ((p > 447) ? 894 - p : p);
    float src = ((float)p + 0.5f) * (1.0f / 14.0f) - 0.5f;
    float fl = floorf(src);
    int i0 = (int)fl;
    float fr = src - fl;
    int c0 = i0 < 0 ? 0 : (i0 > 31 ? 31 : i0);
    int i1 = i0 + 1;
    int c1 = i1 < 0 ? 0 : (i1 > 31 ? 31 : i1);
    float w = 0.f;
    if (c0 == g) w += 1.0f - fr;
    if (c1 == g) w += fr;
    acc += kv * w;
  }
  W[idx] = acc / ksum;
}

// ---------------------------------------------------------------------------
// 6) anomaly_map = W · md_grid · W^T
// ---------------------------------------------------------------------------
__global__ __launch_bounds__(256) void map_stage1_kernel(
    const float* __restrict__ md, const float* __restrict__ W,
    float* __restrict__ tmp) {  // 8 x 448 x 32
  int idx = blockIdx.x * 256 + threadIdx.x;
  if (idx >= 8 * 448 * 32) return;
  int gx = idx & 31;
  int y  = (idx >> 5) % 448;
  int b  = idx / (448 * 32);
  const float* w = W + y * 32;
  const float* m = md + b * 1024 + gx;
  float s = 0.f;
#pragma unroll
  for (int gy = 0; gy < 32; ++gy) s += w[gy] * m[gy * 32];
  tmp[idx] = s;
}

__global__ __launch_bounds__(256) void map_stage2_kernel(
    const float* __restrict__ tmp, const float* __restrict__ W,
    float* __restrict__ out) {  // 8 x 448 x 448
  int idx = blockIdx.x * 256 + threadIdx.x;
  if (idx >= 8 * 448 * 448) return;
  int x    = idx % 448;
  int ypos = idx / 448;  // b*448 + y
  const float* w = W + x * 32;
  const float* t = tmp + ypos * 32;
  float s = 0.f;
#pragma unroll
  for (int gx = 0; gx < 32; ++gx) s += w[gx] * t[gx];
  out[idx] = s;
}

// ---------------------------------------------------------------------------
extern "C" void kernel_launch(void* const* d_in, const int* in_sizes, int n_in,
                              void* d_out, int out_size, void* d_ws, size_t ws_size,
                              hipStream_t stream) {
  const float* features = (const float*)d_in[0];   // 8*1024*384
  const float* bank     = (const float*)d_in[1];   // 65536*384
  float* out = (float*)d_out;                      // [8 scores][8*448*448 map]

  char* ws = (char*)d_ws;
  char*  mb8     = ws;                              // 25,165,824 B
  char*  f8      = ws + 25165824;                   //  3,145,728 B
  float* sB      = (float*)(ws + 28311552);         //    262,144 B
  float* sA      = (float*)(ws + 28573696);         //     32,768 B
  float* partial = (float*)(ws + 28606464);         //  1,048,576 B
  float* md      = (float*)(ws + 29655040);         //     32,768 B
  float* W       = (float*)(ws + 29687808);         //     57,344 B
  float* tmp     = (float*)(ws + 29745152);         //    458,752 B

  quantize_rows_kernel<<<NROW_B / 4, 256, 0, stream>>>(bank, mb8, sB, NROW_B);
  quantize_rows_kernel<<<NROW_F / 4, 256, 0, stream>>>(features, f8, sA, NROW_F);
  maxsim_kernel<<<NWG, 256, 0, stream>>>(f8, mb8, sA, sB, partial);
  combine_kernel<<<NROW_F / 256, 256, 0, stream>>>(partial, md);
  topk_kernel<<<8, 256, 0, stream>>>(md, out);
  build_w_kernel<<<(448 * 32 + 255) / 256, 256, 0, stream>>>(W);
  map_stage1_kernel<<<(8 * 448 * 32 + 255) / 256, 256, 0, stream>>>(md, W, tmp);
  map_stage2_kernel<<<(8 * 448 * 448 + 255) / 256, 256, 0, stream>>>(tmp, W, out + 8);
}

// Round 17
// 240.172 us; speedup vs baseline: 1.0312x; 1.0312x over previous
//
#include <hip/hip_runtime.h>
#include <hip/hip_bf16.h>

#define NROW_F 8192
#define NROW_B 65536
#define KDIM   384
#define BM 128
#define BN 128
#define NSUB 16
#define NGRP (NROW_B / (BN * NSUB))      // 32
#define NBM  (NROW_F / BM)               // 64
#define NWG  (NBM * NGRP)                // 2048

// LDS (80 KB -> 2 blocks/CU): A staging 48K (prologue only), B tri-buf, sB
#define LDSA 0                 // 6 * 8192 = 49152
#define LDSB 49152             // 3 * 8192 = 24576
#define LDSS 73728             // 8192 (2048 f32 sB slice)
#define LDSR 49152             // epilogue red[2][128] aliases B
#define LDS_TOT 81920

typedef int   i32x4 __attribute__((ext_vector_type(4)));
typedef float f32x4 __attribute__((ext_vector_type(4)));

static __device__ __forceinline__ void stage16(const void* g, void* l) {
  __builtin_amdgcn_global_load_lds(
      (const __attribute__((address_space(1))) unsigned int*)g,
      (__attribute__((address_space(3))) unsigned int*)l, 16, 0, 0);
}

// ---------------------------------------------------------------------------
// 1) L2-normalize rows + symmetric i8 quantization with per-row scale.
//    Half-wave (32 lanes) per row, float4 loads / char4 stores (G13).
// ---------------------------------------------------------------------------
__global__ __launch_bounds__(256) void quantize_rows_kernel(
    const float* __restrict__ in, char* __restrict__ out8,
    float* __restrict__ scales, int nrows) {
  int row = blockIdx.x * 8 + (threadIdx.x >> 5);
  int l   = threadIdx.x & 31;
  if (row >= nrows) return;
  const f32x4* r = (const f32x4*)(in + (size_t)row * KDIM);
  f32x4 v[3];
  float ss = 0.f, mx = 0.f;
#pragma unroll
  for (int i = 0; i < 3; ++i) {
    v[i] = r[l + i * 32];
#pragma unroll
    for (int j = 0; j < 4; ++j) {
      ss += v[i][j] * v[i][j];
      mx = fmaxf(mx, fabsf(v[i][j]));
    }
  }
#pragma unroll
  for (int d = 1; d < 32; d <<= 1) {   // xor keeps lanes in their 32-group
    ss += __shfl_xor(ss, d, 64);
    mx = fmaxf(mx, __shfl_xor(mx, d, 64));
  }
  mx = fmaxf(mx, 1e-30f);
  float inv = rsqrtf(fmaxf(ss, 1e-24f));
  float scl = 127.0f / mx;
  if (l == 0) scales[row] = mx * inv * (1.0f / 127.0f);
  char* o = out8 + (size_t)row * KDIM;
#pragma unroll
  for (int i = 0; i < 3; ++i) {
    char4 c;
    c.x = (char)__float2int_rn(v[i][0] * scl);
    c.y = (char)__float2int_rn(v[i][1] * scl);
    c.z = (char)__float2int_rn(v[i][2] * scl);
    c.w = (char)__float2int_rn(v[i][3] * scl);
    *(char4*)(o + (l + i * 32) * 4) = c;
  }
}

// ---------------------------------------------------------------------------
// 2) maxsim: UNCHANGED from round 16 (182 us plateau; banked).
// ---------------------------------------------------------------------------
__global__ __launch_bounds__(256, 2) void maxsim_kernel(
    const char* __restrict__ F8,    // 8192 x 384 i8
    const char* __restrict__ B8,    // 65536 x 384 i8
    const float* __restrict__ sA,   // 8192
    const float* __restrict__ sB,   // 65536
    float* __restrict__ partial) {  // NGRP x 8192 (max sim)
  __shared__ __align__(16) char smem[LDS_TOT];

  const int tid  = threadIdx.x;
  const int wv   = tid >> 6;         // 0..3
  const int lane = tid & 63;
  const int l15  = lane & 15;
  const int lhi  = lane >> 4;
  const int wr   = wv >> 1;          // 0..1 (row half)
  const int wc   = wv & 1;           // 0..1 (col half)

  const int wg  = (blockIdx.x & 7) * (NWG / 8) + (blockIdx.x >> 3);
  const int bm  = wg & (NBM - 1);
  const int grp = wg >> 6;
  const size_t brow = (size_t)bm * BM;

  const int srow = tid >> 2;                           // 0..63
  const int gsw  = (tid & 3) ^ ((tid >> 3) & 3);       // inverse write swizzle

  {
    const char* gA = F8 + (size_t)(brow + srow) * KDIM + gsw * 16;
    char* lA = smem + LDSA + wv * 1024;
#pragma unroll
    for (int kt = 0; kt < 6; ++kt) {
      stage16(gA + kt * 64,             lA + kt * 8192);
      stage16(gA + kt * 64 + 64 * KDIM, lA + kt * 8192 + 4096);
    }
  }
  {
    const char* gs = (const char*)(sB + (size_t)grp * 2048) + tid * 16;
    stage16(gs,        smem + LDSS + wv * 1024);
    stage16(gs + 4096, smem + LDSS + 4096 + wv * 1024);
  }

  auto stageB = [&](int s2, int koff, int buf) {
    const char* g = B8 + ((size_t)grp * 2048 + s2 * 128 + srow) * KDIM
                    + koff * 64 + gsw * 16;
    char* l = smem + LDSB + buf * 8192 + wv * 1024;
    stage16(g, l);
    stage16(g + (size_t)64 * KDIM, l + 4096);
  };
  stageB(0, 0, 0);
  stageB(0, 1, 1);
  stageB(0, 2, 2);

  const int cof = ((l15 >> 1) & 3) << 4;

  auto ldA8 = [&](int k6, int m) -> i32x4 {
    int byte = k6 * 8192 + (wr * 64 + m * 16 + l15) * 64 + ((lhi << 4) ^ cof);
    return *reinterpret_cast<const i32x4*>(smem + LDSA + byte);
  };
  auto ldB8 = [&](int buf, int n) -> i32x4 {
    int byte = buf * 8192 + (wc * 64 + n * 16 + l15) * 64 + ((lhi << 4) ^ cof);
    return *reinterpret_cast<const i32x4*>(smem + LDSB + byte);
  };

  i32x4 acc[4][4];
  f32x4 vm[4];
#pragma unroll
  for (int m = 0; m < 4; ++m) {
    vm[m] = f32x4{-1e30f, -1e30f, -1e30f, -1e30f};
#pragma unroll
    for (int n = 0; n < 4; ++n) acc[m][n] = i32x4{0, 0, 0, 0};
  }

  asm volatile("s_waitcnt vmcnt(4)" ::: "memory");
  __builtin_amdgcn_s_barrier();

  i32x4 a[6][4];
#pragma unroll
  for (int k6 = 0; k6 < 6; ++k6)
#pragma unroll
    for (int m = 0; m < 4; ++m) a[k6][m] = ldA8(k6, m);

  i32x4 bA[4], bB[4];
#pragma unroll
  for (int n = 0; n < 4; ++n) bA[n] = ldB8(0, n);
  asm volatile("s_waitcnt lgkmcnt(0)" ::: "memory");

#define PHASE(K6, BC, BN_) do {                                               \
    asm volatile("s_waitcnt vmcnt(2)" ::: "memory");                          \
    __builtin_amdgcn_s_barrier();                                             \
    __builtin_amdgcn_sched_barrier(0);                                        \
    _Pragma("unroll")                                                         \
    for (int n = 0; n < 4; ++n) BN_[n] = ldB8(((K6) + 1) % 3, n);             \
    {                                                                         \
      const int s2 = ((K6) < 3) ? sub : ((sub + 1) & (NSUB - 1));             \
      stageB(s2, ((K6) + 3) % 6, (K6) % 3);                                   \
    }                                                                         \
    __builtin_amdgcn_sched_barrier(0);                                        \
    __builtin_amdgcn_s_setprio(1);                                            \
    _Pragma("unroll")                                                         \
    for (int n = 0; n < 4; ++n)                                               \
      _Pragma("unroll")                                                       \
      for (int m = 0; m < 4; ++m)                                             \
        acc[m][n] = __builtin_amdgcn_mfma_i32_16x16x64_i8(                    \
            a[K6][m], BC[n], acc[m][n], 0, 0, 0);                             \
    __builtin_amdgcn_s_setprio(0);                                            \
    asm volatile("s_waitcnt lgkmcnt(0)" ::: "memory");                        \
    __builtin_amdgcn_sched_barrier(0);                                        \
  } while (0)

  for (int sub = 0; sub < NSUB; ++sub) {
    PHASE(0, bA, bB);
    PHASE(1, bB, bA);
    PHASE(2, bA, bB);
    PHASE(3, bB, bA);
    PHASE(4, bA, bB);
    PHASE(5, bB, bA);
    float sb[4];
#pragma unroll
    for (int n = 0; n < 4; ++n)
      sb[n] = *reinterpret_cast<const float*>(
          smem + LDSS + (sub * 128 + wc * 64 + n * 16 + l15) * 4);
#pragma unroll
    for (int m = 0; m < 4; ++m) {
#pragma unroll
      for (int n = 0; n < 4; ++n)
#pragma unroll
        for (int j = 0; j < 4; ++j)
          vm[m][j] = fmaxf(vm[m][j], (float)acc[m][n][j] * sb[n]);
#pragma unroll
      for (int n = 0; n < 4; ++n) acc[m][n] = i32x4{0, 0, 0, 0};
    }
  }
#undef PHASE

  asm volatile("s_waitcnt vmcnt(0)" ::: "memory");
#pragma unroll
  for (int d = 1; d < 16; d <<= 1)
#pragma unroll
    for (int m = 0; m < 4; ++m)
#pragma unroll
      for (int j = 0; j < 4; ++j)
        vm[m][j] = fmaxf(vm[m][j], __shfl_xor(vm[m][j], d, 64));

  float* red = (float*)(smem + LDSR);
  __syncthreads();
  if (l15 == 0) {
#pragma unroll
    for (int m = 0; m < 4; ++m)
#pragma unroll
      for (int j = 0; j < 4; ++j)
        red[wc * 128 + wr * 64 + m * 16 + lhi * 4 + j] = vm[m][j];
  }
  __syncthreads();
  if (tid < BM) {
    float x = fmaxf(red[tid], red[128 + tid]);
    partial[(size_t)grp * NROW_F + brow + tid] = x * sA[brow + tid];
  }
}

// ---------------------------------------------------------------------------
// 3) combine (blocks 0..31) + build W (blocks 32..87) fused.
//    md = clip(1 - max_c partial, 0, 2); W = blur ∘ bilinear (448 x 32).
// ---------------------------------------------------------------------------
__global__ __launch_bounds__(256) void combw_kernel(
    const float* __restrict__ partial, float* __restrict__ md,
    float* __restrict__ W) {
  if (blockIdx.x < 32) {
    int r = blockIdx.x * 256 + threadIdx.x;
    float m = -1e30f;
#pragma unroll
    for (int c = 0; c < NGRP; ++c) m = fmaxf(m, partial[(size_t)c * NROW_F + r]);
    float d = 1.0f - m;
    md[r] = fminf(fmaxf(d, 0.0f), 2.0f);
    return;
  }
  int idx = (blockIdx.x - 32) * 256 + threadIdx.x;   // < 448*32 = 14336
  int y = idx >> 5, g = idx & 31;
  float ksum = 0.f, acc = 0.f;
#pragma unroll
  for (int t = -16; t <= 16; ++t) {
    float ft = (float)t * 0.25f;
    float kv = expf(-0.5f * ft * ft);
    ksum += kv;
    int p = y + t;
    p = (p < 0) ? -p : ((p > 447) ? 894 - p : p);
    float src = ((float)p + 0.5f) * (1.0f / 14.0f) - 0.5f;
    float fl = floorf(src);
    int i0 = (int)fl;
    float fr = src - fl;
    int c0 = i0 < 0 ? 0 : (i0 > 31 ? 31 : i0);
    int i1 = i0 + 1;
    int c1 = i1 < 0 ? 0 : (i1 > 31 ? 31 : i1);
    float w = 0.f;
    if (c0 == g) w += 1.0f - fr;
    if (c1 == g) w += fr;
    acc += kv * w;
  }
  W[idx] = acc / ksum;
}

// ---------------------------------------------------------------------------
// 4) top-10 mean per batch, straight from partial (combine fused), 1 wave,
//    register-resident, shuffle-only (no LDS, no syncthreads).
// ---------------------------------------------------------------------------
__global__ __launch_bounds__(64) void topk_kernel(
    const float* __restrict__ partial, float* __restrict__ out) {
  int b = blockIdx.x, lane = threadIdx.x;
  float vals[16];
#pragma unroll
  for (int k = 0; k < 16; ++k) {
    int r = b * 1024 + k * 64 + lane;
    float m = -1e30f;
#pragma unroll
    for (int c = 0; c < NGRP; ++c) m = fmaxf(m, partial[(size_t)c * NROW_F + r]);
    float d = 1.0f - m;
    vals[k] = fminf(fmaxf(d, 0.0f), 2.0f);
  }
  float total = 0.f;
  for (int it = 0; it < 10; ++it) {
    float lb = vals[0]; int li = 0;
#pragma unroll
    for (int k = 1; k < 16; ++k)
      if (vals[k] > lb) { lb = vals[k]; li = k; }
    float wm = lb;
#pragma unroll
    for (int d = 1; d < 64; d <<= 1) wm = fmaxf(wm, __shfl_xor(wm, d, 64));
    unsigned long long mask = __ballot(lb == wm);
    int winner = (int)(__ffsll((unsigned long long)mask) - 1);
    bool kill = (lane == winner);
#pragma unroll
    for (int k = 0; k < 16; ++k)         // static indices (rule #20)
      vals[k] = (kill && k == li) ? -1e30f : vals[k];
    total += wm;
  }
  if (lane == 0) out[b] = total * 0.1f;
}

// ---------------------------------------------------------------------------
// 5) anomaly_map = W · md_grid · W^T, fused: one block per (b, y).
// ---------------------------------------------------------------------------
__global__ __launch_bounds__(256) void map_kernel(
    const float* __restrict__ md, const float* __restrict__ W,
    float* __restrict__ out) {  // 8 x 448 x 448
  __shared__ float tmpv[32];
  int y = blockIdx.x % 448;
  int b = blockIdx.x / 448;
  int tid = threadIdx.x;
  if (tid < 32) {
    const float* w = W + y * 32;
    const float* m = md + b * 1024 + tid;
    float s = 0.f;
#pragma unroll
    for (int gy = 0; gy < 32; ++gy) s += w[gy] * m[gy * 32];
    tmpv[tid] = s;
  }
  __syncthreads();
  for (int x = tid; x < 448; x += 256) {
    const float* w = W + x * 32;
    float s = 0.f;
#pragma unroll
    for (int gx = 0; gx < 32; ++gx) s += w[gx] * tmpv[gx];
    out[(size_t)blockIdx.x * 448 + x] = s;
  }
}

// ---------------------------------------------------------------------------
extern "C" void kernel_launch(void* const* d_in, const int* in_sizes, int n_in,
                              void* d_out, int out_size, void* d_ws, size_t ws_size,
                              hipStream_t stream) {
  const float* features = (const float*)d_in[0];   // 8*1024*384
  const float* bank     = (const float*)d_in[1];   // 65536*384
  float* out = (float*)d_out;                      // [8 scores][8*448*448 map]

  char* ws = (char*)d_ws;
  char*  mb8     = ws;                              // 25,165,824 B
  char*  f8      = ws + 25165824;                   //  3,145,728 B
  float* sB      = (float*)(ws + 28311552);         //    262,144 B
  float* sA      = (float*)(ws + 28573696);         //     32,768 B
  float* partial = (float*)(ws + 28606464);         //  1,048,576 B
  float* md      = (float*)(ws + 29655040);         //     32,768 B
  float* W       = (float*)(ws + 29687808);         //     57,344 B

  quantize_rows_kernel<<<NROW_B / 8, 256, 0, stream>>>(bank, mb8, sB, NROW_B);
  quantize_rows_kernel<<<NROW_F / 8, 256, 0, stream>>>(features, f8, sA, NROW_F);
  maxsim_kernel<<<NWG, 256, 0, stream>>>(f8, mb8, sA, sB, partial);
  combw_kernel<<<88, 256, 0, stream>>>(partial, md, W);
  topk_kernel<<<8, 64, 0, stream>>>(partial, out);
  map_kernel<<<8 * 448, 256, 0, stream>>>(md, W, out + 8);
}